// Round 7
// baseline (4918.934 us; speedup 1.0000x reference)
//
#include <hip/hip_runtime.h>
#include <stdint.h>

// Problem constants
#define G 8
#define H 512
#define I_RAW 1028
#define I_PAD 1056          // padded K for the input GEMM (multiple of 32)
#define BB 128              // batch
#define TT 64               // seq len
#define GH (G*H)            // 4096
#define G3H (G*3*H)         // 12288
#define M_TOT (BB*TT)       // 8192
#define N3H (3*H)           // 1536

typedef __attribute__((ext_vector_type(8))) short bf16x8;
typedef __attribute__((ext_vector_type(4))) float f32x4;
typedef __attribute__((ext_vector_type(4))) unsigned short u16x4;

__device__ __forceinline__ unsigned short f2bf(float f) {
  unsigned int u = __float_as_uint(f);
  u += 0x7fffu + ((u >> 16) & 1u);   // round-to-nearest-even
  return (unsigned short)(u >> 16);
}
__device__ __forceinline__ float bf2f(unsigned short h) {
  return __uint_as_float(((unsigned int)h) << 16);
}

// ---------------- pack kernels ----------------
__global__ void k_pack_x(const float* __restrict__ z, const float* __restrict__ a,
                         unsigned short* __restrict__ xb) {
  int idx = blockIdx.x * 256 + threadIdx.x;
  if (idx >= M_TOT * I_PAD) return;
  int m = idx / I_PAD, i = idx % I_PAD;
  int b = m >> 6, t = m & 63;
  float v = 0.f;
  if (i < 4)            v = a[((size_t)b * TT + t) * 4 + i];
  else if (i < I_RAW)   v = z[((size_t)b * TT + t) * 1024 + (i - 4)];
  xb[idx] = f2bf(v);
}

__global__ void k_pack_wih(const float* __restrict__ w, unsigned short* __restrict__ wb) {
  int idx = blockIdx.x * 256 + threadIdx.x;
  if (idx >= G * N3H * I_PAD) return;
  int gj = idx / I_PAD, i = idx % I_PAD;   // gj = g*1536 + j
  float v = (i < I_RAW) ? w[(size_t)gj * I_RAW + i] : 0.f;
  wb[idx] = f2bf(v);
}

__global__ void k_pack_whh(const float* __restrict__ w, unsigned short* __restrict__ wb) {
  int idx = blockIdx.x * 256 + threadIdx.x;
  if (idx >= G * N3H * H) return;
  wb[idx] = f2bf(w[idx]);
}

__global__ void k_init_h(const float* __restrict__ h, unsigned short* __restrict__ hb0,
                         int* __restrict__ flags) {
  int idx = blockIdx.x * 256 + threadIdx.x;
  if (idx < G * 32 * 8) flags[idx] = 0;        // per (g, wg, wave) step flags
  if (idx >= BB * GH) return;
  hb0[idx] = f2bf(h[idx]);
}

// ---------------- input-projection GEMM (time-chunked, tl-major rows) ----------------
// Chunk row rc = tl*128 + b (tl = t - t0). Each 128-row m-tile = one timestep.
// Output layout (lane-matched to k_scan): per (tl, batch-quad bq, g, col i):
// 12 ushorts = 24B = {q0: j0..j3, q1: j0..j3, q2: j0..j3} (dense, no pad).
#define LROW 80   // LDS row stride in bytes (64B data + 16B pad)

__launch_bounds__(256, 2)
__global__ void k_xproj(const unsigned short* __restrict__ xb,
                        const unsigned short* __restrict__ wihb,
                        unsigned short* __restrict__ xp3,
                        int t0) {
  __shared__ char lA[128 * LROW];
  __shared__ char lB[128 * LROW];
  int blk = blockIdx.x;
  int by = blk / (G3H / 128);       // m-tile = timestep tl
  int bx = blk % (G3H / 128);       // 96 n-tiles
  int m0 = by * 128, n0 = bx * 128;
  int tid = threadIdx.x;
  int lane = tid & 63, wave = tid >> 6;
  int wm = (wave >> 1) * 64, wn = (wave & 1) * 64;

  f32x4 acc[4][4] = {};

  for (int kt = 0; kt < I_PAD / 32; ++kt) {
    int k0 = kt * 32;
#pragma unroll
    for (int p = 0; p < 2; ++p) {
      int row = p * 64 + (tid >> 2);
      int c = (tid & 3) * 16;  // byte within 64B row
      int rc = m0 + row;                       // chunk row
      int b = rc & (BB - 1), tl = rc >> 7;     // batch, chunk-local t
      const char* srcA = (const char*)&xb[(size_t)(b * TT + t0 + tl) * I_PAD + k0] + c;
      *(uint4*)(lA + row * LROW + c) = *(const uint4*)srcA;
      const char* srcB = (const char*)&wihb[(size_t)(n0 + row) * I_PAD + k0] + c;
      *(uint4*)(lB + row * LROW + c) = *(const uint4*)srcB;
    }
    __syncthreads();

    bf16x8 af[4], bf[4];
#pragma unroll
    for (int mt = 0; mt < 4; ++mt) {
      int r = wm + mt * 16 + (lane & 15);
      af[mt] = *(const bf16x8*)(lA + r * LROW + ((lane >> 4) * 16));
    }
#pragma unroll
    for (int nt = 0; nt < 4; ++nt) {
      int r = wn + nt * 16 + (lane & 15);
      bf[nt] = *(const bf16x8*)(lB + r * LROW + ((lane >> 4) * 16));
    }
#pragma unroll
    for (int mt = 0; mt < 4; ++mt)
#pragma unroll
      for (int nt = 0; nt < 4; ++nt)
        acc[mt][nt] = __builtin_amdgcn_mfma_f32_16x16x32_bf16(af[mt], bf[nt], acc[mt][nt], 0, 0, 0);
    __syncthreads();
  }

  // epilogue: D[row][col], col = lane&15, row = (lane>>4)*4 + j  [m89-verified]
  // j-quad == batch-quad (tl-major rows) -> one 8B ushort4 store per (mt,nt).
#pragma unroll
  for (int mt = 0; mt < 4; ++mt)
#pragma unroll
    for (int nt = 0; nt < 4; ++nt) {
      int m = m0 + wm + mt * 16 + (lane >> 4) * 4;   // j=0 row
      int tl = m >> 7;
      int bq = (m & (BB - 1)) >> 2;
      int n = n0 + wn + nt * 16 + (lane & 15);
      int g = n / N3H;
      int rem = n - g * N3H;
      int q = rem >> 9;
      int i = rem & (H - 1);
      u16x4 v;
      v[0] = f2bf(acc[mt][nt][0]);
      v[1] = f2bf(acc[mt][nt][1]);
      v[2] = f2bf(acc[mt][nt][2]);
      v[3] = f2bf(acc[mt][nt][3]);
      size_t addr = ((((size_t)tl * (BB / 4) + bq) * G + g) * H + i) * 12 + q * 4;
      *(u16x4*)&xp3[addr] = v;
    }
}

// ---------------- persistent recurrent scan (cooperative) ----------------
// grid 256 = g(8, fastest -> XCD-pinned blk%8) x 32 i-tiles of 16 cols.
// 512 threads = 8 waves; wave w owns batch rows w*16..w*16+15 FOR THE WHOLE SCAN.
// Per-wave-slice sync: wave w's next-step A-rows are produced by wave w of every
// wg of its g, so each wave independently: compute -> h-store -> RELEASE flag
// [g][wgi][w] -> poll 32 flags [g][*][w] -> acquire fence. NO __syncthreads in
// the loop: the 8 waves drift in phase and hide each other's load/poll latency.
__launch_bounds__(512, 2)
__global__ void k_scan(const unsigned short* __restrict__ xp3,
                       const unsigned short* __restrict__ whhb,
                       const float* __restrict__ b_ih,
                       const float* __restrict__ b_hh,
                       const float* __restrict__ hsrc, int hstride,
                       unsigned short* __restrict__ hbuf0,
                       unsigned short* __restrict__ hbuf1,
                       float* __restrict__ out,
                       int* __restrict__ flags,
                       int t0, int Tc) {
  __shared__ char wlds[48 * 1024];   // [q][kt][lane] 16B fragments, linear
  int blk = blockIdx.x;
  int g = blk & 7;
  int wgi = blk >> 3;                // wg index within g: 0..31
  int i0 = wgi << 4;
  int tid = threadIdx.x, lane = tid & 63, wave = tid >> 6;
  const unsigned short* wg_w = whhb + (size_t)g * N3H * H;

  // stage W fragments: slot s = q*1024 + kt*64 + l
  for (int s = tid; s < 3072; s += 512) {
    int q = s >> 10, kt = (s >> 6) & 15, l = s & 63;
    int j = q * H + i0 + (l & 15);
    int k = kt * 32 + (l >> 4) * 8;
    *(bf16x8*)(wlds + (size_t)s * 16) = *(const bf16x8*)&wg_w[(size_t)j * H + k];
  }

  int ic = lane & 15;
  int i = i0 + ic;
  float brc = b_ih[g * N3H + 0 * H + i] + b_hh[g * N3H + 0 * H + i];
  float bzc = b_ih[g * N3H + 1 * H + i] + b_hh[g * N3H + 1 * H + i];
  float bin = b_ih[g * N3H + 2 * H + i];
  float bhn = b_hh[g * N3H + 2 * H + i];

  // h_prev f32 in regs: rows b_j = wave*16 + (lane>>4)*4 + j, col i
  float hprev[4];
#pragma unroll
  for (int j = 0; j < 4; ++j) {
    int b = wave * 16 + (lane >> 4) * 4 + j;
    hprev[j] = hsrc[(size_t)b * hstride + g * H + i];
  }

  int arow = wave * 16 + (lane & 15);   // A-fragment batch row
  int akoff = (lane >> 4) * 8;

  // flags: [g][wgi][wave]
  int* my_flag = &flags[(g * 32 + wgi) * 8 + wave];
  int* poll_base = &flags[g * 32 * 8 + wave];     // + wgi*8

  // per-lane xp base: (bq, g, i) fixed; 12 ushorts per (bq,g,i) unit (dense)
  int bq = wave * 4 + (lane >> 4);
  const unsigned short* xbase = xp3 + ((((size_t)bq) * G + g) * H + i) * 12;
  const size_t xstep = (size_t)(BB / 4) * G * H * 12;

  __syncthreads();   // wlds ready (only block-wide sync; loop below is per-wave)

  u16x4 xq[3];
#pragma unroll
  for (int q = 0; q < 3; ++q) xq[q] = *(const u16x4*)(xbase + q * 4);

  for (int tl = 0; tl < Tc; ++tl) {
    int t = t0 + tl;
    const unsigned short* hin = (t & 1) ? hbuf1 : hbuf0;
    unsigned short* hout = (t & 1) ? hbuf0 : hbuf1;

    // A loads (own 16 rows), independent -> issued as a batch
    bf16x8 af[16];
#pragma unroll
    for (int kt = 0; kt < 16; ++kt)
      af[kt] = *(const bf16x8*)&hin[(size_t)arow * GH + g * H + kt * 32 + akoff];

    f32x4 acc[3] = {};
#pragma unroll
    for (int kt = 0; kt < 16; ++kt) {
#pragma unroll
      for (int q = 0; q < 3; ++q) {
        bf16x8 wf = *(const bf16x8*)(wlds + ((size_t)(q * 16 + kt) * 64 + lane) * 16);
        acc[q] = __builtin_amdgcn_mfma_f32_16x16x32_bf16(af[kt], wf, acc[q], 0, 0, 0);
      }
    }

    // fused GRU gates; rows b = wave*16 + (lane>>4)*4 + j, col i
    float hn4[4];
#pragma unroll
    for (int j = 0; j < 4; ++j) {
      int b = wave * 16 + (lane >> 4) * 4 + j;
      float xr = bf2f(xq[0][j]);
      float xz = bf2f(xq[1][j]);
      float xn = bf2f(xq[2][j]);
      float r = 1.f / (1.f + __expf(-(xr + acc[0][j] + brc)));
      float u = 1.f / (1.f + __expf(-(xz + acc[1][j] + bzc)));
      float nn = xn + bin + r * (acc[2][j] + bhn);
      float th = 1.f - 2.f / (1.f + __expf(2.f * nn));   // tanh
      float hnew = (1.f - u) * th + u * hprev[j];
      hprev[j] = hnew;
      hn4[j] = hnew;
      hout[(size_t)b * GH + g * H + i] = f2bf(hnew);   // h store (pre-release)
    }

    // release store: drains this wave's h-stores (vmcnt) then publishes step
    __hip_atomic_store(my_flag, t + 1, __ATOMIC_RELEASE, __HIP_MEMORY_SCOPE_AGENT);

    // overlap with the poll: out f32 stores + next-step xp prefetch (into regs)
#pragma unroll
    for (int j = 0; j < 4; ++j) {
      int b = wave * 16 + (lane >> 4) * 4 + j;
      out[((size_t)b * TT + t) * GH + g * H + i] = hn4[j];
    }
    if (tl + 1 < Tc) {
      const unsigned short* xb2 = xbase + (size_t)(tl + 1) * xstep;
#pragma unroll
      for (int q = 0; q < 3; ++q) xq[q] = *(const u16x4*)(xb2 + q * 4);
    }

    if (tl != Tc - 1) {
      // per-wave poll: lane l watches flags[g][l&31][wave]
      int target = t + 1;
      for (;;) {
        int f = __hip_atomic_load(&poll_base[(lane & 31) * 8], __ATOMIC_RELAXED,
                                  __HIP_MEMORY_SCOPE_AGENT);
        if (__ballot(f >= target) == ~0ull) break;
        __builtin_amdgcn_s_sleep(1);
      }
      __builtin_amdgcn_fence(__ATOMIC_ACQUIRE, "agent");  // L1 inv; h-loads -> L2
    }
  }
}

// ---------------- launch ----------------
extern "C" void kernel_launch(void* const* d_in, const int* in_sizes, int n_in,
                              void* d_out, int out_size, void* d_ws, size_t ws_size,
                              hipStream_t stream) {
  const float* z    = (const float*)d_in[0];
  const float* a    = (const float*)d_in[1];
  const float* h0   = (const float*)d_in[2];
  const float* Wih  = (const float*)d_in[3];
  const float* Whh  = (const float*)d_in[4];
  const float* bih  = (const float*)d_in[5];
  const float* bhh  = (const float*)d_in[6];
  float* out = (float*)d_out;

  // workspace layout (bytes)
  char* ws = (char*)d_ws;
  const size_t XB_OFF  = 0;                                     // 17.3 MB
  const size_t WIH_OFF = XB_OFF  + (size_t)M_TOT * I_PAD * 2;   // 26.0 MB
  const size_t WHH_OFF = WIH_OFF + (size_t)G * N3H * I_PAD * 2; // 12.6 MB
  const size_t HB_OFF  = WHH_OFF + (size_t)G * N3H * H * 2;     // 2 x 1 MB bf16 h ping-pong
  const size_t BAR_OFF = HB_OFF  + 2 * (size_t)BB * GH * 2;     // 8 KB step flags
  const size_t XP_OFF  = BAR_OFF + 8192;
  const size_t FIXED   = XP_OFF;

  // adaptive time-chunking: largest power-of-2 Tc<=64 whose xp3 chunk fits ws
  const size_t XP_ROW = (size_t)(BB / 4) * G * H * 12 * 2;   // bytes per time step = 3 MiB
  int tcShift = 6;
  while (tcShift > 0 && FIXED + (XP_ROW << tcShift) > ws_size) --tcShift;
  const int Tc = 1 << tcShift;

  unsigned short* xb   = (unsigned short*)(ws + XB_OFF);
  unsigned short* wihb = (unsigned short*)(ws + WIH_OFF);
  unsigned short* whhb = (unsigned short*)(ws + WHH_OFF);
  unsigned short* hb   = (unsigned short*)(ws + HB_OFF);
  int*            flags = (int*)(ws + BAR_OFF);
  unsigned short* xp3  = (unsigned short*)(ws + XP_OFF);

  unsigned short* hbuf0 = hb;
  unsigned short* hbuf1 = hb + (size_t)BB * GH;

  // pack
  {
    int n = M_TOT * I_PAD;
    k_pack_x<<<(n + 255) / 256, 256, 0, stream>>>(z, a, xb);
  }
  {
    int n = G * N3H * I_PAD;
    k_pack_wih<<<(n + 255) / 256, 256, 0, stream>>>(Wih, wihb);
  }
  {
    int n = G * N3H * H;
    k_pack_whh<<<(n + 255) / 256, 256, 0, stream>>>(Whh, whhb);
  }
  {
    int n = BB * GH;
    k_init_h<<<(n + 255) / 256, 256, 0, stream>>>(h0, hbuf0, flags);
  }

  // time-chunked: xproj GEMM for chunk, then one persistent scan kernel
  for (int t0 = 0; t0 < TT; t0 += Tc) {
    k_xproj<<<Tc * (G3H / 128), 256, 0, stream>>>(xb, wihb, xp3, t0);

    const float* hsrc = (t0 == 0) ? h0 : (const float*)(out + (size_t)(t0 - 1) * GH);
    int hstride = (t0 == 0) ? GH : TT * GH;
    int t0v = t0, tcv = Tc;
    void* args[] = { (void*)&xp3, (void*)&whhb, (void*)&bih, (void*)&bhh,
                     (void*)&hsrc, (void*)&hstride, (void*)&hbuf0, (void*)&hbuf1,
                     (void*)&out, (void*)&flags, (void*)&t0v, (void*)&tcv };
    hipLaunchCooperativeKernel((void*)k_scan, dim3(256), dim3(512), args, 0, stream);
  }
}

// Round 8
// 4299.001 us; speedup vs baseline: 1.1442x; 1.1442x over previous
//
#include <hip/hip_runtime.h>
#include <stdint.h>

// Problem constants
#define G 8
#define H 512
#define I_RAW 1028
#define I_PAD 1056          // padded K for the input GEMM (multiple of 32)
#define BB 128              // batch
#define TT 64               // seq len
#define GH (G*H)            // 4096
#define G3H (G*3*H)         // 12288
#define M_TOT (BB*TT)       // 8192
#define N3H (3*H)           // 1536

typedef __attribute__((ext_vector_type(8))) short bf16x8;
typedef __attribute__((ext_vector_type(4))) float f32x4;
typedef __attribute__((ext_vector_type(4))) unsigned short u16x4;

__device__ __forceinline__ unsigned short f2bf(float f) {
  unsigned int u = __float_as_uint(f);
  u += 0x7fffu + ((u >> 16) & 1u);   // round-to-nearest-even
  return (unsigned short)(u >> 16);
}
__device__ __forceinline__ float bf2f(unsigned short h) {
  return __uint_as_float(((unsigned int)h) << 16);
}

// ---------------- pack kernels ----------------
__global__ void k_pack_x(const float* __restrict__ z, const float* __restrict__ a,
                         unsigned short* __restrict__ xb) {
  int idx = blockIdx.x * 256 + threadIdx.x;
  if (idx >= M_TOT * I_PAD) return;
  int m = idx / I_PAD, i = idx % I_PAD;
  int b = m >> 6, t = m & 63;
  float v = 0.f;
  if (i < 4)            v = a[((size_t)b * TT + t) * 4 + i];
  else if (i < I_RAW)   v = z[((size_t)b * TT + t) * 1024 + (i - 4)];
  xb[idx] = f2bf(v);
}

__global__ void k_pack_wih(const float* __restrict__ w, unsigned short* __restrict__ wb) {
  int idx = blockIdx.x * 256 + threadIdx.x;
  if (idx >= G * N3H * I_PAD) return;
  int gj = idx / I_PAD, i = idx % I_PAD;   // gj = g*1536 + j
  float v = (i < I_RAW) ? w[(size_t)gj * I_RAW + i] : 0.f;
  wb[idx] = f2bf(v);
}

// W_hh packed fragment-linear for k_scan:
// unit index u = ((gw*12 + ct)*16 + kt)*64 + lane, gw = g*8+wave, ct = q*4+it.
// Each unit = 8 ushorts (one bf16x8 B-fragment slice):
// j = q*512 + wave*64 + it*16 + (lane&15), k = kt*32 + (lane>>4)*8 + e.
__global__ void k_pack_whh(const float* __restrict__ w, unsigned short* __restrict__ wb) {
  int idx = blockIdx.x * 256 + threadIdx.x;
  if (idx >= G * 8 * 12 * 16 * 64) return;
  int lane = idx & 63;
  int t1 = idx >> 6;
  int kt = t1 & 15;
  int t2 = t1 >> 4;
  int ct = t2 % 12;
  int gw = t2 / 12;
  int g = gw >> 3, wave = gw & 7;
  int q = ct >> 2, it = ct & 3;
  int j = q * 512 + wave * 64 + it * 16 + (lane & 15);
  int k = kt * 32 + (lane >> 4) * 8;
  const float* src = &w[((size_t)g * N3H + j) * H + k];
#pragma unroll
  for (int e = 0; e < 8; ++e)
    wb[(size_t)idx * 8 + e] = f2bf(src[e]);
}

// ---------------- input-projection GEMM (time-chunked, tl-major rows) ----------------
// Chunk row rc = tl*128 + b (tl = t - t0). Each 128-row m-tile = one timestep.
// Output layout (lane-matched to k_scan): per (tl, batch-quad bq, g, col i):
// 12 ushorts = 24B = {q0: j0..j3, q1: j0..j3, q2: j0..j3} (dense, no pad).
#define LROW 80   // LDS row stride in bytes (64B data + 16B pad)

__launch_bounds__(256, 2)
__global__ void k_xproj(const unsigned short* __restrict__ xb,
                        const unsigned short* __restrict__ wihb,
                        unsigned short* __restrict__ xp3,
                        int t0) {
  __shared__ char lA[128 * LROW];
  __shared__ char lB[128 * LROW];
  int blk = blockIdx.x;
  int by = blk / (G3H / 128);       // m-tile = timestep tl
  int bx = blk % (G3H / 128);       // 96 n-tiles
  int m0 = by * 128, n0 = bx * 128;
  int tid = threadIdx.x;
  int lane = tid & 63, wave = tid >> 6;
  int wm = (wave >> 1) * 64, wn = (wave & 1) * 64;

  f32x4 acc[4][4] = {};

  for (int kt = 0; kt < I_PAD / 32; ++kt) {
    int k0 = kt * 32;
#pragma unroll
    for (int p = 0; p < 2; ++p) {
      int row = p * 64 + (tid >> 2);
      int c = (tid & 3) * 16;  // byte within 64B row
      int rc = m0 + row;                       // chunk row
      int b = rc & (BB - 1), tl = rc >> 7;     // batch, chunk-local t
      const char* srcA = (const char*)&xb[(size_t)(b * TT + t0 + tl) * I_PAD + k0] + c;
      *(uint4*)(lA + row * LROW + c) = *(const uint4*)srcA;
      const char* srcB = (const char*)&wihb[(size_t)(n0 + row) * I_PAD + k0] + c;
      *(uint4*)(lB + row * LROW + c) = *(const uint4*)srcB;
    }
    __syncthreads();

    bf16x8 af[4], bf[4];
#pragma unroll
    for (int mt = 0; mt < 4; ++mt) {
      int r = wm + mt * 16 + (lane & 15);
      af[mt] = *(const bf16x8*)(lA + r * LROW + ((lane >> 4) * 16));
    }
#pragma unroll
    for (int nt = 0; nt < 4; ++nt) {
      int r = wn + nt * 16 + (lane & 15);
      bf[nt] = *(const bf16x8*)(lB + r * LROW + ((lane >> 4) * 16));
    }
#pragma unroll
    for (int mt = 0; mt < 4; ++mt)
#pragma unroll
      for (int nt = 0; nt < 4; ++nt)
        acc[mt][nt] = __builtin_amdgcn_mfma_f32_16x16x32_bf16(af[mt], bf[nt], acc[mt][nt], 0, 0, 0);
    __syncthreads();
  }

  // epilogue: D[row][col], col = lane&15, row = (lane>>4)*4 + j  [m89-verified]
  // j-quad == batch-quad (tl-major rows) -> one 8B ushort4 store per (mt,nt).
#pragma unroll
  for (int mt = 0; mt < 4; ++mt)
#pragma unroll
    for (int nt = 0; nt < 4; ++nt) {
      int m = m0 + wm + mt * 16 + (lane >> 4) * 4;   // j=0 row
      int tl = m >> 7;
      int bq = (m & (BB - 1)) >> 2;
      int n = n0 + wn + nt * 16 + (lane & 15);
      int g = n / N3H;
      int rem = n - g * N3H;
      int q = rem >> 9;
      int i = rem & (H - 1);
      u16x4 v;
      v[0] = f2bf(acc[mt][nt][0]);
      v[1] = f2bf(acc[mt][nt][1]);
      v[2] = f2bf(acc[mt][nt][2]);
      v[3] = f2bf(acc[mt][nt][3]);
      size_t addr = ((((size_t)tl * (BB / 4) + bq) * G + g) * H + i) * 12 + q * 4;
      *(u16x4*)&xp3[addr] = v;
    }
}

// ---------------- recurrent scan: 64 INDEPENDENT workgroups ----------------
// wg = (g = blk&7, btile = blk>>3): owns batch rows btile*16..+15 of block g for
// the whole scan. h state: f32 in regs (C-fragment layout, same thread owns the
// same (b,i) every step) + bf16 copy in double-buffered LDS A-tile for MFMA.
// Per step: A-frags from LDS -> 1536 MFMA (W streamed from L2, fragment-linear,
// L2-resident: 8 same-g wgs per XCD share one 1.57MB W) -> gates -> write LDS
// A[nxt] + out. ONE __syncthreads per step. NO inter-wg sync of any kind.
__launch_bounds__(512, 2)
__global__ void k_scan(const unsigned short* __restrict__ xp3,
                       const unsigned short* __restrict__ wpk,
                       const float* __restrict__ b_ih,
                       const float* __restrict__ b_hh,
                       const float* __restrict__ hsrc, int hstride,
                       float* __restrict__ out,
                       int t0, int Tc) {
  __shared__ unsigned short Ab[2][16 * 512];   // [buf][swizzled 16x512 bf16]
  int blk = blockIdx.x;
  int g = blk & 7;                 // plain round-robin dispatch: blk&7 ~ XCD pin
  int btile = blk >> 3;
  int tid = threadIdx.x, lane = tid & 63, wave = tid >> 6;

  // biases for this thread's 4 i-cols (one per it)
  float brc[4], bzc[4], bin4[4], bhn4[4];
#pragma unroll
  for (int it = 0; it < 4; ++it) {
    int i = wave * 64 + it * 16 + (lane & 15);
    brc[it]  = b_ih[g * N3H + 0 * H + i] + b_hh[g * N3H + 0 * H + i];
    bzc[it]  = b_ih[g * N3H + 1 * H + i] + b_hh[g * N3H + 1 * H + i];
    bin4[it] = b_ih[g * N3H + 2 * H + i];
    bhn4[it] = b_hh[g * N3H + 2 * H + i];
  }

  // h_prev f32 in regs: [it][j] -> row btile*16 + (lane>>4)*4 + j, col i(it)
  float hprev[4][4];
#pragma unroll
  for (int it = 0; it < 4; ++it)
#pragma unroll
    for (int j = 0; j < 4; ++j) {
      int b = btile * 16 + (lane >> 4) * 4 + j;
      int i = wave * 64 + it * 16 + (lane & 15);
      hprev[it][j] = hsrc[(size_t)b * hstride + g * H + i];
    }

  // initial A staging: hsrc -> bf16 swizzled LDS Ab[0]
  for (int s = tid; s < 16 * 512; s += 512) {
    int r = s >> 9, c = s & 511;
    float v = hsrc[(size_t)(btile * 16 + r) * hstride + g * H + c];
    Ab[0][(r * 1024 + ((c * 2) ^ ((r & 7) << 4))) >> 1] = f2bf(v);
  }

  // per-wave W base (fragment-linear packed)
  const unsigned short* wbase = wpk + ((size_t)(g * 8 + wave) * 12 * 16 * 64) * 8;

  // xp pointers: bq = btile*4 + (lane>>4)
  int bq = btile * 4 + (lane >> 4);
  const size_t xstep = (size_t)(BB / 4) * G * H * 12;
  const unsigned short* xptr[4];
#pragma unroll
  for (int it = 0; it < 4; ++it) {
    int i = wave * 64 + it * 16 + (lane & 15);
    xptr[it] = xp3 + (((size_t)bq * G + g) * H + i) * 12;
  }

  __syncthreads();

  for (int tl = 0; tl < Tc; ++tl) {
    int t = t0 + tl;
    int cur = tl & 1, nxt = cur ^ 1;

    // A fragments for this step (row = lane&15, k = kt*32 + (lane>>4)*8)
    bf16x8 af[16];
    {
      int row = lane & 15;
      int sw = (row & 7) << 4;
#pragma unroll
      for (int kt = 0; kt < 16; ++kt) {
        int cb = kt * 64 + ((lane >> 4) * 16);
        af[kt] = *(const bf16x8*)&Ab[cur][(row * 1024 + (cb ^ sw)) >> 1];
      }
    }

    // xp gate-inputs for this step (independent loads, issue early)
    u16x4 xq[4][3];
#pragma unroll
    for (int it = 0; it < 4; ++it)
#pragma unroll
      for (int q = 0; q < 3; ++q)
        xq[it][q] = *(const u16x4*)(xptr[it] + (size_t)tl * xstep + q * 4);

#pragma unroll
    for (int it = 0; it < 4; ++it) {
      // 3 gate columns for this i-tile: ct = q*4 + it
      f32x4 ar = {}, az = {}, an = {};
      const unsigned short* wr = wbase + (size_t)((0 * 4 + it) * 16) * 64 * 8;
      const unsigned short* wz = wbase + (size_t)((1 * 4 + it) * 16) * 64 * 8;
      const unsigned short* wn = wbase + (size_t)((2 * 4 + it) * 16) * 64 * 8;
#pragma unroll
      for (int kt = 0; kt < 16; ++kt) {
        bf16x8 fr = *(const bf16x8*)(wr + ((size_t)kt * 64 + lane) * 8);
        bf16x8 fz = *(const bf16x8*)(wz + ((size_t)kt * 64 + lane) * 8);
        bf16x8 fn = *(const bf16x8*)(wn + ((size_t)kt * 64 + lane) * 8);
        ar = __builtin_amdgcn_mfma_f32_16x16x32_bf16(af[kt], fr, ar, 0, 0, 0);
        az = __builtin_amdgcn_mfma_f32_16x16x32_bf16(af[kt], fz, az, 0, 0, 0);
        an = __builtin_amdgcn_mfma_f32_16x16x32_bf16(af[kt], fn, an, 0, 0, 0);
      }

      int i = wave * 64 + it * 16 + (lane & 15);
      int rsw = 0;
#pragma unroll
      for (int j = 0; j < 4; ++j) {
        int row = (lane >> 4) * 4 + j;        // 0..15 within tile
        int b = btile * 16 + row;
        float xr = bf2f(xq[it][0][j]);
        float xz = bf2f(xq[it][1][j]);
        float xn = bf2f(xq[it][2][j]);
        float r = 1.f / (1.f + __expf(-(xr + ar[j] + brc[it])));
        float u = 1.f / (1.f + __expf(-(xz + az[j] + bzc[it])));
        float nn = xn + bin4[it] + r * (an[j] + bhn4[it]);
        float th = 1.f - 2.f / (1.f + __expf(2.f * nn));   // tanh
        float hnew = (1.f - u) * th + u * hprev[it][j];
        hprev[it][j] = hnew;
        // bf16 h for next step's A-operand (swizzled LDS write)
        Ab[nxt][(row * 1024 + ((i * 2) ^ ((row & 7) << 4))) >> 1] = f2bf(hnew);
        // output
        out[((size_t)b * TT + t) * GH + g * H + i] = hnew;
        (void)rsw;
      }
    }

    __syncthreads();   // Ab[nxt] complete; Ab[cur] reads done
  }
}

// ---------------- launch ----------------
extern "C" void kernel_launch(void* const* d_in, const int* in_sizes, int n_in,
                              void* d_out, int out_size, void* d_ws, size_t ws_size,
                              hipStream_t stream) {
  const float* z    = (const float*)d_in[0];
  const float* a    = (const float*)d_in[1];
  const float* h0   = (const float*)d_in[2];
  const float* Wih  = (const float*)d_in[3];
  const float* Whh  = (const float*)d_in[4];
  const float* bih  = (const float*)d_in[5];
  const float* bhh  = (const float*)d_in[6];
  float* out = (float*)d_out;

  // workspace layout (bytes)
  char* ws = (char*)d_ws;
  const size_t XB_OFF  = 0;                                     // 17.3 MB
  const size_t WIH_OFF = XB_OFF  + (size_t)M_TOT * I_PAD * 2;   // 26.0 MB
  const size_t WPK_OFF = WIH_OFF + (size_t)G * N3H * I_PAD * 2; // 12.6 MB packed W_hh
  const size_t XP_OFF  = WPK_OFF + (size_t)G * N3H * H * 2;
  const size_t FIXED   = XP_OFF;

  // adaptive time-chunking: largest power-of-2 Tc<=64 whose xp3 chunk fits ws
  const size_t XP_ROW = (size_t)(BB / 4) * G * H * 12 * 2;   // bytes per time step = 3 MiB
  int tcShift = 6;
  while (tcShift > 0 && FIXED + (XP_ROW << tcShift) > ws_size) --tcShift;
  const int Tc = 1 << tcShift;

  unsigned short* xb   = (unsigned short*)(ws + XB_OFF);
  unsigned short* wihb = (unsigned short*)(ws + WIH_OFF);
  unsigned short* wpk  = (unsigned short*)(ws + WPK_OFF);
  unsigned short* xp3  = (unsigned short*)(ws + XP_OFF);

  // pack
  {
    int n = M_TOT * I_PAD;
    k_pack_x<<<(n + 255) / 256, 256, 0, stream>>>(z, a, xb);
  }
  {
    int n = G * N3H * I_PAD;
    k_pack_wih<<<(n + 255) / 256, 256, 0, stream>>>(Wih, wihb);
  }
  {
    int n = G * 8 * 12 * 16 * 64;   // fragment units
    k_pack_whh<<<(n + 255) / 256, 256, 0, stream>>>(Whh, wpk);
  }

  // time-chunked: xproj GEMM for chunk, then the independent-wg scan kernel
  for (int t0 = 0; t0 < TT; t0 += Tc) {
    k_xproj<<<Tc * (G3H / 128), 256, 0, stream>>>(xb, wihb, xp3, t0);

    const float* hsrc = (t0 == 0) ? h0 : (const float*)(out + (size_t)(t0 - 1) * GH);
    int hstride = (t0 == 0) ? GH : TT * GH;
    k_scan<<<64, 512, 0, stream>>>(xp3, wpk, bih, bhh, hsrc, hstride, out, t0, Tc);
  }
}

// Round 10
// 1232.104 us; speedup vs baseline: 3.9923x; 3.4892x over previous
//
#include <hip/hip_runtime.h>
#include <stdint.h>

// Problem constants
#define G 8
#define H 512
#define I_RAW 1028
#define I_PAD 1056          // padded K for the input GEMM (multiple of 32)
#define BB 128              // batch
#define TT 64               // seq len
#define GH (G*H)            // 4096
#define G3H (G*3*H)         // 12288
#define M_TOT (BB*TT)       // 8192
#define N3H (3*H)           // 1536

typedef __attribute__((ext_vector_type(8))) short bf16x8;
typedef __attribute__((ext_vector_type(4))) float f32x4;
typedef __attribute__((ext_vector_type(4))) unsigned short u16x4;

__device__ __forceinline__ unsigned short f2bf(float f) {
  unsigned int u = __float_as_uint(f);
  u += 0x7fffu + ((u >> 16) & 1u);   // round-to-nearest-even
  return (unsigned short)(u >> 16);
}
__device__ __forceinline__ float bf2f(unsigned short h) {
  return __uint_as_float(((unsigned int)h) << 16);
}

// ---------------- pack kernels ----------------
__global__ void k_pack_x(const float* __restrict__ z, const float* __restrict__ a,
                         unsigned short* __restrict__ xb) {
  int idx = blockIdx.x * 256 + threadIdx.x;
  if (idx >= M_TOT * I_PAD) return;
  int m = idx / I_PAD, i = idx % I_PAD;
  int b = m >> 6, t = m & 63;
  float v = 0.f;
  if (i < 4)            v = a[((size_t)b * TT + t) * 4 + i];
  else if (i < I_RAW)   v = z[((size_t)b * TT + t) * 1024 + (i - 4)];
  xb[idx] = f2bf(v);
}

__global__ void k_pack_wih(const float* __restrict__ w, unsigned short* __restrict__ wb) {
  int idx = blockIdx.x * 256 + threadIdx.x;
  if (idx >= G * N3H * I_PAD) return;
  int gj = idx / I_PAD, i = idx % I_PAD;   // gj = g*1536 + j
  float v = (i < I_RAW) ? w[(size_t)gj * I_RAW + i] : 0.f;
  wb[idx] = f2bf(v);
}

// W_hh r,z gates packed fragment-linear:
// unit U = (g*8+hs)*8192 + ((gate*4+nt)*16+kt)*64 + lane; 8 ushorts each.
// j = gate*512 + hs*64 + nt*16 + (lane&15); k = kt*32 + (lane>>4)*8.
__global__ void k_pack_wrz(const float* __restrict__ w, unsigned short* __restrict__ wb) {
  int idx = blockIdx.x * 256 + threadIdx.x;
  if (idx >= G * 8 * 8192) return;
  int lane = idx & 63;
  int v = idx >> 6;
  int kt = v & 15; v >>= 4;
  int nt = v & 3;  v >>= 2;
  int gate = v & 1; v >>= 1;
  int hs = v & 7;
  int g = v >> 3;
  int j = gate * 512 + hs * 64 + nt * 16 + (lane & 15);
  int k = kt * 32 + (lane >> 4) * 8;
  const float* src = &w[((size_t)g * N3H + j) * H + k];
#pragma unroll
  for (int e = 0; e < 8; ++e)
    wb[(size_t)idx * 8 + e] = f2bf(src[e]);
}

// W_hh n gate packed: unit U = (g*8+hs)*4096 + (nt*16+kt)*64 + lane.
// (4096 = nt(4) x kt(16) x lane(64) units per (g,hs) slice — R9 bug was 1024.)
__global__ void k_pack_wn(const float* __restrict__ w, unsigned short* __restrict__ wb) {
  int idx = blockIdx.x * 256 + threadIdx.x;
  if (idx >= G * 8 * 4096) return;
  int lane = idx & 63;
  int v = idx >> 6;
  int kt = v & 15; v >>= 4;
  int nt = v & 3;  v >>= 2;
  int hs = v & 7;
  int g = v >> 3;
  int j = 1024 + hs * 64 + nt * 16 + (lane & 15);
  int k = kt * 32 + (lane >> 4) * 8;
  const float* src = &w[((size_t)g * N3H + j) * H + k];
#pragma unroll
  for (int e = 0; e < 8; ++e)
    wb[(size_t)idx * 8 + e] = f2bf(src[e]);
}

// ---------------- input-projection GEMM (time-chunked, tl-major rows) ----------------
// Output layout: per (tl, batch-quad bq, g, col i): 12 ushorts {q0 j0..3, q1, q2}.
#define LROW 80   // LDS row stride in bytes (64B data + 16B pad)

__launch_bounds__(256, 2)
__global__ void k_xproj(const unsigned short* __restrict__ xb,
                        const unsigned short* __restrict__ wihb,
                        unsigned short* __restrict__ xp3,
                        int t0) {
  __shared__ char lA[128 * LROW];
  __shared__ char lB[128 * LROW];
  int blk = blockIdx.x;
  int by = blk / (G3H / 128);       // m-tile = timestep tl
  int bx = blk % (G3H / 128);       // 96 n-tiles
  int m0 = by * 128, n0 = bx * 128;
  int tid = threadIdx.x;
  int lane = tid & 63, wave = tid >> 6;
  int wm = (wave >> 1) * 64, wn = (wave & 1) * 64;

  f32x4 acc[4][4] = {};

  for (int kt = 0; kt < I_PAD / 32; ++kt) {
    int k0 = kt * 32;
#pragma unroll
    for (int p = 0; p < 2; ++p) {
      int row = p * 64 + (tid >> 2);
      int c = (tid & 3) * 16;  // byte within 64B row
      int rc = m0 + row;                       // chunk row
      int b = rc & (BB - 1), tl = rc >> 7;     // batch, chunk-local t
      const char* srcA = (const char*)&xb[(size_t)(b * TT + t0 + tl) * I_PAD + k0] + c;
      *(uint4*)(lA + row * LROW + c) = *(const uint4*)srcA;
      const char* srcB = (const char*)&wihb[(size_t)(n0 + row) * I_PAD + k0] + c;
      *(uint4*)(lB + row * LROW + c) = *(const uint4*)srcB;
    }
    __syncthreads();

    bf16x8 af[4], bf[4];
#pragma unroll
    for (int mt = 0; mt < 4; ++mt) {
      int r = wm + mt * 16 + (lane & 15);
      af[mt] = *(const bf16x8*)(lA + r * LROW + ((lane >> 4) * 16));
    }
#pragma unroll
    for (int nt = 0; nt < 4; ++nt) {
      int r = wn + nt * 16 + (lane & 15);
      bf[nt] = *(const bf16x8*)(lB + r * LROW + ((lane >> 4) * 16));
    }
#pragma unroll
    for (int mt = 0; mt < 4; ++mt)
#pragma unroll
      for (int nt = 0; nt < 4; ++nt)
        acc[mt][nt] = __builtin_amdgcn_mfma_f32_16x16x32_bf16(af[mt], bf[nt], acc[mt][nt], 0, 0, 0);
    __syncthreads();
  }

#pragma unroll
  for (int mt = 0; mt < 4; ++mt)
#pragma unroll
    for (int nt = 0; nt < 4; ++nt) {
      int m = m0 + wm + mt * 16 + (lane >> 4) * 4;   // j=0 row
      int tl = m >> 7;
      int bq = (m & (BB - 1)) >> 2;
      int n = n0 + wn + nt * 16 + (lane & 15);
      int g = n / N3H;
      int rem = n - g * N3H;
      int q = rem >> 9;
      int i = rem & (H - 1);
      u16x4 v;
      v[0] = f2bf(acc[mt][nt][0]);
      v[1] = f2bf(acc[mt][nt][1]);
      v[2] = f2bf(acc[mt][nt][2]);
      v[3] = f2bf(acc[mt][nt][3]);
      size_t addr = ((((size_t)tl * (BB / 4) + bq) * G + g) * H + i) * 12 + q * 4;
      *(u16x4*)&xp3[addr] = v;
    }
}

// ---------------- persistent recurrent scan (cooperative, 4bt x 8hs split) ----------------
// grid 256 = g(8, fastest) x bt(4) x hs(8); 512 thr = 8 waves = mt(2) x nt(4).
// wg owns rows bt*32..+31, cols hs*64..+63 (3 gates). W_r,W_z in 128KB dynamic
// LDS (staged once); W_n in 64 VGPRs (loaded once). h exchange: hx[2] global
// double-buffer; per (g,bt) group of 8 wgs: release flag -> relaxed poll ->
// one agent-acquire fence. Per-step traffic: A-frags 128KB/CU from L2/L3,
// LDS W-reads 256KB/CU. No per-step W fetch.
__launch_bounds__(512, 2)
__global__ void k_scan(const unsigned short* __restrict__ xp3,
                       const unsigned short* __restrict__ wrz,
                       const unsigned short* __restrict__ wnp,
                       const float* __restrict__ b_ih,
                       const float* __restrict__ b_hh,
                       const float* __restrict__ hsrc, int hstride,
                       unsigned short* __restrict__ hx,
                       int* __restrict__ flags,
                       float* __restrict__ out,
                       int t0, int Tc) {
  extern __shared__ char wlds[];   // 131072 B: [gate2][nt4][kt16][lane64] x16B
  int blk = blockIdx.x;
  int g = blk & 7;
  int bt = (blk >> 3) & 3;
  int hs = blk >> 5;
  int tid = threadIdx.x, lane = tid & 63, wave = tid >> 6;
  int mt = wave >> 2, nt = wave & 3;

  // stage W_rz -> LDS (once)
  const unsigned short* wrzb = wrz + (size_t)(g * 8 + hs) * 8192 * 8;
  for (int s = tid; s < 8192; s += 512)
    *(bf16x8*)(wlds + (size_t)s * 16) = *(const bf16x8*)(wrzb + (size_t)s * 8);

  int i = hs * 64 + nt * 16 + (lane & 15);       // this thread's single column
  int rbase = bt * 32 + mt * 16;
  int row4 = (lane >> 4) * 4;

  float brc = b_ih[g * N3H + i]            + b_hh[g * N3H + i];
  float bzc = b_ih[g * N3H + 512 + i]      + b_hh[g * N3H + 512 + i];
  float bin = b_ih[g * N3H + 1024 + i];
  float bhn = b_hh[g * N3H + 1024 + i];

  // W_n fragments resident in regs (step-invariant)
  bf16x8 wnreg[16];
  const unsigned short* wnb = wnp + (size_t)(g * 8 + hs) * 4096 * 8;
#pragma unroll
  for (int kt = 0; kt < 16; ++kt)
    wnreg[kt] = *(const bf16x8*)(wnb + ((size_t)(nt * 16 + kt) * 64 + lane) * 8);

  // h_prev f32 in regs (4 rows x own col)
  float hprev[4];
#pragma unroll
  for (int j = 0; j < 4; ++j) {
    int b = rbase + row4 + j;
    hprev[j] = hsrc[(size_t)b * hstride + g * H + i];
  }

  // init hx[t0&1] with own 32x64 piece of h(t0)
  const size_t HXBUF = (size_t)G * BB * H;
  unsigned short* hx0 = hx + (size_t)(t0 & 1) * HXBUF;
  for (int s = tid; s < 2048; s += 512) {
    int r = s >> 6, c = s & 63;
    int b = bt * 32 + r, ii = hs * 64 + c;
    hx0[((size_t)g * BB + b) * H + ii] = f2bf(hsrc[(size_t)b * hstride + g * H + ii]);
  }
  asm volatile("s_waitcnt vmcnt(0)" ::: "memory");
  __syncthreads();
  int* gflags = flags + (g * 4 + bt) * 32;
  if (tid == 0)
    __hip_atomic_store(&gflags[hs], t0 + 1, __ATOMIC_RELEASE, __HIP_MEMORY_SCOPE_AGENT);

  // xp prefetch for tl=0
  int bq = bt * 8 + mt * 4 + (lane >> 4);
  const unsigned short* xb0 = xp3 + (((size_t)bq * G + g) * H + i) * 12;
  const size_t xstep = (size_t)(BB / 4) * G * H * 12;
  u16x4 xq[3];
#pragma unroll
  for (int q = 0; q < 3; ++q) xq[q] = *(const u16x4*)(xb0 + q * 4);

  for (int tl = 0; tl < Tc; ++tl) {
    int t = t0 + tl;
    const unsigned short* hcur = hx + (size_t)(t & 1) * HXBUF;
    unsigned short* hnxt = hx + (size_t)((t + 1) & 1) * HXBUF;

    // wait for all 8 wgs of this (g,bt) group to have written h(t)
    if (wave == 0) {
      int target = t + 1;
      for (;;) {
        int f = (lane < 8) ? __hip_atomic_load(&gflags[lane], __ATOMIC_RELAXED,
                                               __HIP_MEMORY_SCOPE_AGENT)
                           : target;
        if (__ballot(f >= target) == ~0ull) break;
        __builtin_amdgcn_s_sleep(1);
      }
      __builtin_amdgcn_fence(__ATOMIC_ACQUIRE, "agent");  // one inv per step per wg
    }
    __syncthreads();

    // A fragments: 16 rows x 512 K of h(t) (rows rbase..+15)
    bf16x8 af[16];
    const unsigned short* abase =
        hcur + ((size_t)g * BB + rbase + (lane & 15)) * H + (lane >> 4) * 8;
#pragma unroll
    for (int kt = 0; kt < 16; ++kt)
      af[kt] = *(const bf16x8*)(abase + kt * 32);

    f32x4 ar = {}, az = {}, aN = {};
#pragma unroll
    for (int kt = 0; kt < 16; ++kt) {
      bf16x8 fr = *(const bf16x8*)(wlds + (((size_t)(0 * 4 + nt) * 16 + kt) * 64 + lane) * 16);
      bf16x8 fz = *(const bf16x8*)(wlds + (((size_t)(1 * 4 + nt) * 16 + kt) * 64 + lane) * 16);
      ar = __builtin_amdgcn_mfma_f32_16x16x32_bf16(af[kt], fr, ar, 0, 0, 0);
      az = __builtin_amdgcn_mfma_f32_16x16x32_bf16(af[kt], fz, az, 0, 0, 0);
      aN = __builtin_amdgcn_mfma_f32_16x16x32_bf16(af[kt], wnreg[kt], aN, 0, 0, 0);
    }

    // gates; rows b = rbase + row4 + j, col i
    float hn4[4];
#pragma unroll
    for (int j = 0; j < 4; ++j) {
      int b = rbase + row4 + j;
      float xr = bf2f(xq[0][j]);
      float xz = bf2f(xq[1][j]);
      float xn = bf2f(xq[2][j]);
      float r = 1.f / (1.f + __expf(-(xr + ar[j] + brc)));
      float u = 1.f / (1.f + __expf(-(xz + az[j] + bzc)));
      float nn = xn + bin + r * (aN[j] + bhn);
      float th = 1.f - 2.f / (1.f + __expf(2.f * nn));   // tanh
      float hnew = (1.f - u) * th + u * hprev[j];
      hprev[j] = hnew;
      hn4[j] = hnew;
      hnxt[((size_t)g * BB + b) * H + i] = f2bf(hnew);
    }

    // drain h stores (all waves), then publish
    asm volatile("s_waitcnt vmcnt(0)" ::: "memory");
    __syncthreads();
    if (tid == 0)
      __hip_atomic_store(&gflags[hs], t + 2, __ATOMIC_RELEASE, __HIP_MEMORY_SCOPE_AGENT);

    // overlap next poll: out stores + next xp prefetch (regs, fence-immune)
#pragma unroll
    for (int j = 0; j < 4; ++j) {
      int b = rbase + row4 + j;
      out[((size_t)b * TT + t) * GH + g * H + i] = hn4[j];
    }
    if (tl + 1 < Tc) {
      const unsigned short* xb2 = xb0 + (size_t)(tl + 1) * xstep;
#pragma unroll
      for (int q = 0; q < 3; ++q) xq[q] = *(const u16x4*)(xb2 + q * 4);
    }
  }
}

// ---------------- launch ----------------
extern "C" void kernel_launch(void* const* d_in, const int* in_sizes, int n_in,
                              void* d_out, int out_size, void* d_ws, size_t ws_size,
                              hipStream_t stream) {
  const float* z    = (const float*)d_in[0];
  const float* a    = (const float*)d_in[1];
  const float* h0   = (const float*)d_in[2];
  const float* Wih  = (const float*)d_in[3];
  const float* Whh  = (const float*)d_in[4];
  const float* bih  = (const float*)d_in[5];
  const float* bhh  = (const float*)d_in[6];
  float* out = (float*)d_out;

  // workspace layout (bytes)
  char* ws = (char*)d_ws;
  const size_t XB_OFF  = 0;                                     // 17.3 MB
  const size_t WIH_OFF = XB_OFF  + (size_t)M_TOT * I_PAD * 2;   // 26.0 MB
  const size_t WRZ_OFF = WIH_OFF + (size_t)G * N3H * I_PAD * 2; //  8.4 MB
  const size_t WN_OFF  = WRZ_OFF + (size_t)G * 8 * 8192 * 16;   //  4.2 MB
  const size_t HX_OFF  = WN_OFF  + (size_t)G * 8 * 4096 * 16;   //  2.1 MB (2 bufs)
  const size_t FL_OFF  = HX_OFF  + 2 * (size_t)G * BB * H * 2;  //  4 KB flags
  const size_t XP_OFF  = FL_OFF  + 4096;
  const size_t FIXED   = XP_OFF;

  // adaptive time-chunking
  const size_t XP_ROW = (size_t)(BB / 4) * G * H * 12 * 2;   // 3 MiB per step
  int tcShift = 6;
  while (tcShift > 0 && FIXED + (XP_ROW << tcShift) > ws_size) --tcShift;
  const int Tc = 1 << tcShift;

  unsigned short* xb   = (unsigned short*)(ws + XB_OFF);
  unsigned short* wihb = (unsigned short*)(ws + WIH_OFF);
  unsigned short* wrz  = (unsigned short*)(ws + WRZ_OFF);
  unsigned short* wnp  = (unsigned short*)(ws + WN_OFF);
  unsigned short* hx   = (unsigned short*)(ws + HX_OFF);
  int*            flags = (int*)(ws + FL_OFF);
  unsigned short* xp3  = (unsigned short*)(ws + XP_OFF);

  // allow 128KB dynamic LDS for k_scan (call every time; idempotent)
  (void)hipFuncSetAttribute((const void*)k_scan,
                            hipFuncAttributeMaxDynamicSharedMemorySize, 131072);

  hipMemsetAsync(flags, 0, 4096, stream);

  // pack
  {
    int n = M_TOT * I_PAD;
    k_pack_x<<<(n + 255) / 256, 256, 0, stream>>>(z, a, xb);
  }
  {
    int n = G * N3H * I_PAD;
    k_pack_wih<<<(n + 255) / 256, 256, 0, stream>>>(Wih, wihb);
  }
  {
    int n = G * 8 * 8192;
    k_pack_wrz<<<(n + 255) / 256, 256, 0, stream>>>(Whh, wrz);
  }
  {
    int n = G * 8 * 4096;
    k_pack_wn<<<(n + 255) / 256, 256, 0, stream>>>(Whh, wnp);
  }

  // time-chunked: xproj GEMM, then cooperative scan
  for (int t0 = 0; t0 < TT; t0 += Tc) {
    k_xproj<<<Tc * (G3H / 128), 256, 0, stream>>>(xb, wihb, xp3, t0);

    const float* hsrc = (t0 == 0) ? h0 : (const float*)(out + (size_t)(t0 - 1) * GH);
    int hstride = (t0 == 0) ? GH : TT * GH;
    int t0v = t0, tcv = Tc;
    void* args[] = { (void*)&xp3, (void*)&wrz, (void*)&wnp, (void*)&bih, (void*)&bhh,
                     (void*)&hsrc, (void*)&hstride, (void*)&hx, (void*)&flags,
                     (void*)&out, (void*)&t0v, (void*)&tcv };
    hipLaunchCooperativeKernel((void*)k_scan, dim3(256), dim3(512), args, 131072, stream);
  }
}

// Round 11
// 964.398 us; speedup vs baseline: 5.1005x; 1.2776x over previous
//
#include <hip/hip_runtime.h>
#include <stdint.h>

// Problem constants
#define G 8
#define H 512
#define I_RAW 1028
#define I_PAD 1056          // padded K for the input GEMM (multiple of 32)
#define BB 128              // batch
#define TT 64               // seq len
#define GH (G*H)            // 4096
#define G3H (G*3*H)         // 12288
#define M_TOT (BB*TT)       // 8192
#define N3H (3*H)           // 1536

typedef __attribute__((ext_vector_type(8))) short bf16x8;
typedef __attribute__((ext_vector_type(4))) float f32x4;
typedef __attribute__((ext_vector_type(4))) unsigned short u16x4;

__device__ __forceinline__ unsigned short f2bf(float f) {
  unsigned int u = __float_as_uint(f);
  u += 0x7fffu + ((u >> 16) & 1u);   // round-to-nearest-even
  return (unsigned short)(u >> 16);
}
__device__ __forceinline__ float bf2f(unsigned short h) {
  return __uint_as_float(((unsigned int)h) << 16);
}

// ---------------- pack kernels ----------------
__global__ void k_pack_x(const float* __restrict__ z, const float* __restrict__ a,
                         unsigned short* __restrict__ xb) {
  int idx = blockIdx.x * 256 + threadIdx.x;
  if (idx >= M_TOT * I_PAD) return;
  int m = idx / I_PAD, i = idx % I_PAD;
  int b = m >> 6, t = m & 63;
  float v = 0.f;
  if (i < 4)            v = a[((size_t)b * TT + t) * 4 + i];
  else if (i < I_RAW)   v = z[((size_t)b * TT + t) * 1024 + (i - 4)];
  xb[idx] = f2bf(v);
}

__global__ void k_pack_wih(const float* __restrict__ w, unsigned short* __restrict__ wb) {
  int idx = blockIdx.x * 256 + threadIdx.x;
  if (idx >= G * N3H * I_PAD) return;
  int gj = idx / I_PAD, i = idx % I_PAD;   // gj = g*1536 + j
  float v = (i < I_RAW) ? w[(size_t)gj * I_RAW + i] : 0.f;
  wb[idx] = f2bf(v);
}

// W_hh r,z gates packed fragment-linear:
// unit U = (g*8+hs)*8192 + ((gate*4+nt)*16+kt)*64 + lane; 8 ushorts each.
// j = gate*512 + hs*64 + nt*16 + (lane&15); k = kt*32 + (lane>>4)*8.
__global__ void k_pack_wrz(const float* __restrict__ w, unsigned short* __restrict__ wb) {
  int idx = blockIdx.x * 256 + threadIdx.x;
  if (idx >= G * 8 * 8192) return;
  int lane = idx & 63;
  int v = idx >> 6;
  int kt = v & 15; v >>= 4;
  int nt = v & 3;  v >>= 2;
  int gate = v & 1; v >>= 1;
  int hs = v & 7;
  int g = v >> 3;
  int j = gate * 512 + hs * 64 + nt * 16 + (lane & 15);
  int k = kt * 32 + (lane >> 4) * 8;
  const float* src = &w[((size_t)g * N3H + j) * H + k];
#pragma unroll
  for (int e = 0; e < 8; ++e)
    wb[(size_t)idx * 8 + e] = f2bf(src[e]);
}

// W_hh n gate packed: unit U = (g*8+hs)*4096 + (nt*16+kt)*64 + lane.
__global__ void k_pack_wn(const float* __restrict__ w, unsigned short* __restrict__ wb) {
  int idx = blockIdx.x * 256 + threadIdx.x;
  if (idx >= G * 8 * 4096) return;
  int lane = idx & 63;
  int v = idx >> 6;
  int kt = v & 15; v >>= 4;
  int nt = v & 3;  v >>= 2;
  int hs = v & 7;
  int g = v >> 3;
  int j = 1024 + hs * 64 + nt * 16 + (lane & 15);
  int k = kt * 32 + (lane >> 4) * 8;
  const float* src = &w[((size_t)g * N3H + j) * H + k];
#pragma unroll
  for (int e = 0; e < 8; ++e)
    wb[(size_t)idx * 8 + e] = f2bf(src[e]);
}

// ---------------- input-projection GEMM (time-chunked, tl-major rows) ----------------
// Output layout: per (tl, batch-quad bq, g, col i): 12 ushorts {q0 j0..3, q1, q2}.
#define LROW 80   // LDS row stride in bytes (64B data + 16B pad)

__launch_bounds__(256, 2)
__global__ void k_xproj(const unsigned short* __restrict__ xb,
                        const unsigned short* __restrict__ wihb,
                        unsigned short* __restrict__ xp3,
                        int t0) {
  __shared__ char lA[128 * LROW];
  __shared__ char lB[128 * LROW];
  int blk = blockIdx.x;
  int by = blk / (G3H / 128);       // m-tile = timestep tl
  int bx = blk % (G3H / 128);       // 96 n-tiles
  int m0 = by * 128, n0 = bx * 128;
  int tid = threadIdx.x;
  int lane = tid & 63, wave = tid >> 6;
  int wm = (wave >> 1) * 64, wn = (wave & 1) * 64;

  f32x4 acc[4][4] = {};

  for (int kt = 0; kt < I_PAD / 32; ++kt) {
    int k0 = kt * 32;
#pragma unroll
    for (int p = 0; p < 2; ++p) {
      int row = p * 64 + (tid >> 2);
      int c = (tid & 3) * 16;  // byte within 64B row
      int rc = m0 + row;                       // chunk row
      int b = rc & (BB - 1), tl = rc >> 7;     // batch, chunk-local t
      const char* srcA = (const char*)&xb[(size_t)(b * TT + t0 + tl) * I_PAD + k0] + c;
      *(uint4*)(lA + row * LROW + c) = *(const uint4*)srcA;
      const char* srcB = (const char*)&wihb[(size_t)(n0 + row) * I_PAD + k0] + c;
      *(uint4*)(lB + row * LROW + c) = *(const uint4*)srcB;
    }
    __syncthreads();

    bf16x8 af[4], bf[4];
#pragma unroll
    for (int mt = 0; mt < 4; ++mt) {
      int r = wm + mt * 16 + (lane & 15);
      af[mt] = *(const bf16x8*)(lA + r * LROW + ((lane >> 4) * 16));
    }
#pragma unroll
    for (int nt = 0; nt < 4; ++nt) {
      int r = wn + nt * 16 + (lane & 15);
      bf[nt] = *(const bf16x8*)(lB + r * LROW + ((lane >> 4) * 16));
    }
#pragma unroll
    for (int mt = 0; mt < 4; ++mt)
#pragma unroll
      for (int nt = 0; nt < 4; ++nt)
        acc[mt][nt] = __builtin_amdgcn_mfma_f32_16x16x32_bf16(af[mt], bf[nt], acc[mt][nt], 0, 0, 0);
    __syncthreads();
  }

#pragma unroll
  for (int mt = 0; mt < 4; ++mt)
#pragma unroll
    for (int nt = 0; nt < 4; ++nt) {
      int m = m0 + wm + mt * 16 + (lane >> 4) * 4;   // j=0 row
      int tl = m >> 7;
      int bq = (m & (BB - 1)) >> 2;
      int n = n0 + wn + nt * 16 + (lane & 15);
      int g = n / N3H;
      int rem = n - g * N3H;
      int q = rem >> 9;
      int i = rem & (H - 1);
      u16x4 v;
      v[0] = f2bf(acc[mt][nt][0]);
      v[1] = f2bf(acc[mt][nt][1]);
      v[2] = f2bf(acc[mt][nt][2]);
      v[3] = f2bf(acc[mt][nt][3]);
      size_t addr = ((((size_t)tl * (BB / 4) + bq) * G + g) * H + i) * 12 + q * 4;
      *(u16x4*)&xp3[addr] = v;
    }
}

// ---------------- persistent recurrent scan (cooperative, fence-free) ----------------
// grid 256 = g(8) x bt(4) x hs(8); 512 thr = 8 waves = mt(2) x nt(4).
// W_rz in 128KB LDS (once), W_n in 64 VGPRs (once). A-tile: 32KB LDS [32][512]
// bf16 XOR-swizzled, re-staged per step from hx via L3-coherent loads.
// Exchange protocol (NO fences, NO L2 inv/wb): h-stores sc0|sc1 (write-through
// to memory-side L3, coherent across XCDs) -> per-wave vmcnt(0) -> per-wave
// relaxed flag store -> consumers poll 64 flags (one per lane) relaxed ->
// coherent 8B atomic loads re-stage A-tile. hx double-buffered.
__launch_bounds__(512, 1)
__global__ void k_scan(const unsigned short* __restrict__ xp3,
                       const unsigned short* __restrict__ wrz,
                       const unsigned short* __restrict__ wnp,
                       const float* __restrict__ b_ih,
                       const float* __restrict__ b_hh,
                       const float* __restrict__ hsrc, int hstride,
                       unsigned short* __restrict__ hx,
                       int* __restrict__ flags,
                       float* __restrict__ out,
                       int t0, int Tc) {
  extern __shared__ char lds[];
  char* wlds  = lds;            // 128 KB: W_r,W_z fragments [gate2][nt4][kt16][lane64]x16B
  char* atile = lds + 131072;   // 32 KB: A-tile [32 rows][512 cols] bf16, swizzled

  int blk = blockIdx.x;
  int g  = blk & 7;
  int bt = (blk >> 3) & 3;
  int hs = blk >> 5;
  int tid = threadIdx.x, lane = tid & 63, wave = tid >> 6;
  int mt = wave >> 2, nt = wave & 3;

  // ---- one-time staging ----
  const unsigned short* wrzb = wrz + (size_t)(g * 8 + hs) * 8192 * 8;
  for (int s = tid; s < 8192; s += 512)
    *(bf16x8*)(wlds + (size_t)s * 16) = *(const bf16x8*)(wrzb + (size_t)s * 8);

  bf16x8 wnreg[16];
  const unsigned short* wnb = wnp + (size_t)(g * 8 + hs) * 4096 * 8;
#pragma unroll
  for (int kt = 0; kt < 16; ++kt)
    wnreg[kt] = *(const bf16x8*)(wnb + ((size_t)(nt * 16 + kt) * 64 + lane) * 8);

  int i = hs * 64 + nt * 16 + (lane & 15);   // this thread's output column
  int rbase = bt * 32 + mt * 16;
  int row4 = (lane >> 4) * 4;

  float brc = b_ih[g * N3H + i]       + b_hh[g * N3H + i];
  float bzc = b_ih[g * N3H + 512 + i] + b_hh[g * N3H + 512 + i];
  float bin = b_ih[g * N3H + 1024 + i];
  float bhn = b_hh[g * N3H + 1024 + i];

  float hprev[4];
#pragma unroll
  for (int j = 0; j < 4; ++j)
    hprev[j] = hsrc[(size_t)(rbase + row4 + j) * hstride + g * H + i];

  // prologue: A-tile <- h(t0) from hsrc (f32, plain loads: kernel-boundary visible)
  {
    int r = tid >> 4, c0 = (tid & 15) * 32;
    const float* src = &hsrc[(size_t)(bt * 32 + r) * hstride + g * H + c0];
    int sb = r * 1024 + c0 * 2, sw = (r & 7) << 4;
#pragma unroll
    for (int n = 0; n < 4; ++n) {
      unsigned short tmp[8];
#pragma unroll
      for (int e = 0; e < 8; ++e) tmp[e] = f2bf(src[n * 8 + e]);
      *(uint4*)(atile + ((sb + n * 16) ^ sw)) = *(const uint4*)tmp;
    }
  }

  int* gflags = flags + (g * 4 + bt) * 64;   // 64 producer-wave flags per (g,bt)
  int myflag = hs * 8 + wave;

  int bq = bt * 8 + mt * 4 + (lane >> 4);
  const unsigned short* xb0 = xp3 + (((size_t)bq * G + g) * H + i) * 12;
  const size_t xstep = (size_t)(BB / 4) * G * H * 12;

  __syncthreads();

  u16x4 xq[3];
#pragma unroll
  for (int q = 0; q < 3; ++q) xq[q] = *(const u16x4*)(xb0 + q * 4);

  const size_t HXBUF = (size_t)G * BB * H;
  int rloc = mt * 16 + (lane & 15);          // A-tile row this lane reads
  int swa = (rloc & 7) << 4;

  for (int tl = 0; tl < Tc; ++tl) {
    int t = t0 + tl;
    unsigned short* hnxt = hx + (size_t)((t + 1) & 1) * HXBUF;

    // A fragments from LDS A-tile (holds h(t))
    bf16x8 af[16];
    const char* ap = atile + rloc * 1024;
#pragma unroll
    for (int kt = 0; kt < 16; ++kt) {
      int cb = kt * 64 + ((lane >> 4) * 16);
      af[kt] = *(const bf16x8*)(ap + (cb ^ swa));
    }
    __syncthreads();   // all waves' af reads done -> A-tile writable below

    f32x4 ar = {}, az = {}, aN = {};
#pragma unroll
    for (int kt = 0; kt < 16; ++kt) {
      bf16x8 fr = *(const bf16x8*)(wlds + (((size_t)(0 * 4 + nt) * 16 + kt) * 64 + lane) * 16);
      bf16x8 fz = *(const bf16x8*)(wlds + (((size_t)(1 * 4 + nt) * 16 + kt) * 64 + lane) * 16);
      ar = __builtin_amdgcn_mfma_f32_16x16x32_bf16(af[kt], fr, ar, 0, 0, 0);
      az = __builtin_amdgcn_mfma_f32_16x16x32_bf16(af[kt], fz, az, 0, 0, 0);
      aN = __builtin_amdgcn_mfma_f32_16x16x32_bf16(af[kt], wnreg[kt], aN, 0, 0, 0);
    }

    // gates; rows b = rbase + row4 + j, col i. h-stores: L3-coherent 2B stores.
    float hn4[4];
#pragma unroll
    for (int j = 0; j < 4; ++j) {
      float xr = bf2f(xq[0][j]);
      float xz = bf2f(xq[1][j]);
      float xn = bf2f(xq[2][j]);
      float r = 1.f / (1.f + __expf(-(xr + ar[j] + brc)));
      float u = 1.f / (1.f + __expf(-(xz + az[j] + bzc)));
      float nn = xn + bin + r * (aN[j] + bhn);
      float th = 1.f - 2.f / (1.f + __expf(2.f * nn));   // tanh
      float hnew = (1.f - u) * th + u * hprev[j];
      hprev[j] = hnew;
      hn4[j] = hnew;
      unsigned int hb = f2bf(hnew);
      void* dst = (void*)&hnxt[((size_t)g * BB + rbase + row4 + j) * H + i];
      asm volatile("global_store_short %0, %1, off sc0 sc1" :: "v"(dst), "v"(hb) : "memory");
    }
    // per-wave: drain own coherent stores, publish own flag (relaxed, no fence)
    asm volatile("s_waitcnt vmcnt(0)" ::: "memory");
    if (lane == 0)
      __hip_atomic_store(&gflags[myflag], t + 1, __ATOMIC_RELAXED, __HIP_MEMORY_SCOPE_AGENT);

    // out stores (plain) overlap the poll
#pragma unroll
    for (int j = 0; j < 4; ++j)
      out[((size_t)(rbase + row4 + j) * TT + t) * GH + g * H + i] = hn4[j];

    if (tl + 1 < Tc) {
      // next-step xp prefetch (regs)
      const unsigned short* xb2 = xb0 + (size_t)(tl + 1) * xstep;
#pragma unroll
      for (int q = 0; q < 3; ++q) xq[q] = *(const u16x4*)(xb2 + q * 4);

      // per-wave poll: lane l watches producer-wave flag l (relaxed, L3)
      int target = t + 1;
      for (;;) {
        int f = __hip_atomic_load(&gflags[lane], __ATOMIC_RELAXED, __HIP_MEMORY_SCOPE_AGENT);
        if (__ballot(f >= target) == ~0ull) break;
        __builtin_amdgcn_s_sleep(2);
      }
      asm volatile("" ::: "memory");   // compiler barrier: stage loads stay below

      // re-stage A-tile <- h(t+1) via coherent 8B loads (64B per thread)
      int r2 = tid >> 4, c0 = (tid & 15) * 32;
      unsigned long long* src =
          (unsigned long long*)&hnxt[((size_t)g * BB + bt * 32 + r2) * H + c0];
      unsigned long long v8[8];
#pragma unroll
      for (int n = 0; n < 8; ++n)
        v8[n] = __hip_atomic_load(&src[n], __ATOMIC_RELAXED, __HIP_MEMORY_SCOPE_AGENT);
      int sb = r2 * 1024 + c0 * 2, sw2 = (r2 & 7) << 4;
#pragma unroll
      for (int n = 0; n < 4; ++n) {
        uint4 w4;
        w4.x = (unsigned)v8[2 * n];       w4.y = (unsigned)(v8[2 * n] >> 32);
        w4.z = (unsigned)v8[2 * n + 1];   w4.w = (unsigned)(v8[2 * n + 1] >> 32);
        *(uint4*)(atile + ((sb + n * 16) ^ sw2)) = w4;
      }
    }
    __syncthreads();   // stage complete before next step's af reads
  }
}

// ---------------- launch ----------------
extern "C" void kernel_launch(void* const* d_in, const int* in_sizes, int n_in,
                              void* d_out, int out_size, void* d_ws, size_t ws_size,
                              hipStream_t stream) {
  const float* z    = (const float*)d_in[0];
  const float* a    = (const float*)d_in[1];
  const float* h0   = (const float*)d_in[2];
  const float* Wih  = (const float*)d_in[3];
  const float* Whh  = (const float*)d_in[4];
  const float* bih  = (const float*)d_in[5];
  const float* bhh  = (const float*)d_in[6];
  float* out = (float*)d_out;

  // workspace layout (bytes)
  char* ws = (char*)d_ws;
  const size_t XB_OFF  = 0;                                     // 17.3 MB
  const size_t WIH_OFF = XB_OFF  + (size_t)M_TOT * I_PAD * 2;   // 26.0 MB
  const size_t WRZ_OFF = WIH_OFF + (size_t)G * N3H * I_PAD * 2; //  8.4 MB
  const size_t WN_OFF  = WRZ_OFF + (size_t)G * 8 * 8192 * 16;   //  4.2 MB
  const size_t HX_OFF  = WN_OFF  + (size_t)G * 8 * 4096 * 16;   //  2.1 MB (2 bufs)
  const size_t FL_OFF  = HX_OFF  + 2 * (size_t)G * BB * H * 2;  //  8 KB flags
  const size_t XP_OFF  = FL_OFF  + 8192;
  const size_t FIXED   = XP_OFF;

  // adaptive time-chunking
  const size_t XP_ROW = (size_t)(BB / 4) * G * H * 12 * 2;   // 3 MiB per step
  int tcShift = 6;
  while (tcShift > 0 && FIXED + (XP_ROW << tcShift) > ws_size) --tcShift;
  const int Tc = 1 << tcShift;

  unsigned short* xb   = (unsigned short*)(ws + XB_OFF);
  unsigned short* wihb = (unsigned short*)(ws + WIH_OFF);
  unsigned short* wrz  = (unsigned short*)(ws + WRZ_OFF);
  unsigned short* wnp  = (unsigned short*)(ws + WN_OFF);
  unsigned short* hx   = (unsigned short*)(ws + HX_OFF);
  int*            flags = (int*)(ws + FL_OFF);
  unsigned short* xp3  = (unsigned short*)(ws + XP_OFF);

  // allow 160KB dynamic LDS for k_scan (idempotent)
  (void)hipFuncSetAttribute((const void*)k_scan,
                            hipFuncAttributeMaxDynamicSharedMemorySize, 163840);

  hipMemsetAsync(flags, 0, 8192, stream);

  // pack
  {
    int n = M_TOT * I_PAD;
    k_pack_x<<<(n + 255) / 256, 256, 0, stream>>>(z, a, xb);
  }
  {
    int n = G * N3H * I_PAD;
    k_pack_wih<<<(n + 255) / 256, 256, 0, stream>>>(Wih, wihb);
  }
  {
    int n = G * 8 * 8192;
    k_pack_wrz<<<(n + 255) / 256, 256, 0, stream>>>(Whh, wrz);
  }
  {
    int n = G * 8 * 4096;
    k_pack_wn<<<(n + 255) / 256, 256, 0, stream>>>(Whh, wnp);
  }

  // time-chunked: xproj GEMM, then cooperative fence-free scan
  for (int t0 = 0; t0 < TT; t0 += Tc) {
    k_xproj<<<Tc * (G3H / 128), 256, 0, stream>>>(xb, wihb, xp3, t0);

    const float* hsrc = (t0 == 0) ? h0 : (const float*)(out + (size_t)(t0 - 1) * GH);
    int hstride = (t0 == 0) ? GH : TT * GH;
    int t0v = t0, tcv = Tc;
    void* args[] = { (void*)&xp3, (void*)&wrz, (void*)&wnp, (void*)&bih, (void*)&bhh,
                     (void*)&hsrc, (void*)&hstride, (void*)&hx, (void*)&flags,
                     (void*)&out, (void*)&t0v, (void*)&tcv };
    hipLaunchCooperativeKernel((void*)k_scan, dim3(256), dim3(512), args, 163840, stream);
  }
}